// Round 4
// baseline (217.395 us; speedup 1.0000x reference)
//
#include <hip/hip_runtime.h>
#include <hip/hip_bf16.h>

// y = q_tok(x) @ q_grp(W)^T + bias, factored exactly:
//   q(x) = g_x * s_x[m], q(W) = g_w * s_w[n,grp] (grp=128 along K)
//   y[m,n] = s_x[m] * sum_grp s_w[n,grp] * (sum_{k in grp} g_x g_w)
// R4: inner sums via mfma_scale_f32_16x16x128_f8f6f4 (HW scales = 1.0) --
// one instruction per K-group, 2x FLOP per MFMA-pipe cycle vs bf16/fp8
// (m148 ladder step). Group sums are fp32-EXACT (grid products are
// multiples of 0.25, bounded), rescale per group in VALU (hidden, m114).

#define M_TOK 2048
#define N_OUT 4096
#define K_IN  4096
#define XBLK  2048
#define WBLK  16384

typedef __attribute__((ext_vector_type(4))) int   int4v;
typedef __attribute__((ext_vector_type(8))) int   int8v;
typedef __attribute__((ext_vector_type(4))) float floatx4;

// fp4-e2m1 nearest-grid, encoded as OCP e4m3 byte.
// Tie rule matches np argmin over ascending grid: positive ties -> LOWER
// magnitude (<=), negative ties -> HIGHER magnitude (<).
__device__ __forceinline__ unsigned int q_fp8(float v) {
    float a = fabsf(v);
    bool p = (v > 0.0f);
    unsigned int m;
    if      (p ? (a <= 0.25f) : (a < 0.25f)) m = 0x00u;  // 0
    else if (p ? (a <= 0.75f) : (a < 0.75f)) m = 0x30u;  // 0.5
    else if (p ? (a <= 1.25f) : (a < 1.25f)) m = 0x38u;  // 1
    else if (p ? (a <= 1.75f) : (a < 1.75f)) m = 0x3Cu;  // 1.5
    else if (p ? (a <= 2.5f)  : (a < 2.5f))  m = 0x40u;  // 2
    else if (p ? (a <= 3.5f)  : (a < 3.5f))  m = 0x44u;  // 3
    else if (p ? (a <= 5.0f)  : (a < 5.0f))  m = 0x48u;  // 4
    else                                     m = 0x4Cu;  // 6
    return m | ((__float_as_uint(v) >> 24) & 0x80u);
}

// ---------- fused quant: blocks [0,XBLK) per-token x, rest per-group w ----------
__global__ __launch_bounds__(256) void quant_fused_kernel(
    const float* __restrict__ x, const float* __restrict__ w,
    unsigned char* __restrict__ xq, float* __restrict__ sx,
    unsigned char* __restrict__ wq, float* __restrict__ swt)
{
    const int t = threadIdx.x;
    const int lane = t & 63, wid = t >> 6;

    if (blockIdx.x < XBLK) {
        const int row = blockIdx.x;
        const float* xr = x + (size_t)row * K_IN;
        float vals[16];
        float amax = 0.0f;
        #pragma unroll
        for (int i = 0; i < 4; i++) {
            float4 v = *(const float4*)(xr + i * 1024 + t * 4);
            v.x = fminf(fmaxf(v.x, -3.0f), 3.0f);
            v.y = fminf(fmaxf(v.y, -3.0f), 3.0f);
            v.z = fminf(fmaxf(v.z, -3.0f), 3.0f);
            v.w = fminf(fmaxf(v.w, -3.0f), 3.0f);
            vals[i*4+0] = v.x; vals[i*4+1] = v.y; vals[i*4+2] = v.z; vals[i*4+3] = v.w;
            amax = fmaxf(amax, fmaxf(fmaxf(fabsf(v.x), fabsf(v.y)),
                                     fmaxf(fabsf(v.z), fabsf(v.w))));
        }
        #pragma unroll
        for (int off = 32; off; off >>= 1)
            amax = fmaxf(amax, __shfl_xor(amax, off));
        __shared__ float smax[4];
        if (lane == 0) smax[wid] = amax;
        __syncthreads();
        amax = fmaxf(fmaxf(smax[0], smax[1]), fmaxf(smax[2], smax[3]));

        const float scale = amax / 6.0f;
        if (t == 0) sx[row] = scale;
        unsigned char* xo = xq + (size_t)row * K_IN;
        #pragma unroll
        for (int i = 0; i < 4; i++) {
            unsigned int u = q_fp8(vals[i*4+0] / scale)
                           | (q_fp8(vals[i*4+1] / scale) << 8)
                           | (q_fp8(vals[i*4+2] / scale) << 16)
                           | (q_fp8(vals[i*4+3] / scale) << 24);
            *(unsigned int*)(xo + i * 1024 + t * 4) = u;
        }
    } else {
        // block covers 1024 floats = row n=b>>2, k in [(b&3)*1024, +1024);
        // 32-lane cluster per group of 128
        const int b = blockIdx.x - XBLK;
        const float* base = w + (size_t)b * 1024 + t * 4;
        float4 v = *(const float4*)base;
        float amax = fmaxf(fmaxf(fabsf(v.x), fabsf(v.y)),
                           fmaxf(fabsf(v.z), fabsf(v.w)));
        #pragma unroll
        for (int off = 16; off; off >>= 1)
            amax = fmaxf(amax, __shfl_xor(amax, off));
        const float scale = amax / 6.0f;
        const int n  = b >> 2;
        const int gk = (b & 3) * 8 + (t >> 5);
        if ((lane & 31) == 0) swt[(size_t)gk * N_OUT + n] = scale;  // transposed [grp][n]
        unsigned int u = q_fp8(v.x / scale)
                       | (q_fp8(v.y / scale) << 8)
                       | (q_fp8(v.z / scale) << 16)
                       | (q_fp8(v.w / scale) << 24);
        *(unsigned int*)(wq + (size_t)b * 1024 + t * 4) = u;
    }
}

// ---------- async 16B global->LDS ----------
__device__ __forceinline__ void gld16(const unsigned char* g, unsigned char* l) {
    __builtin_amdgcn_global_load_lds(
        (const __attribute__((address_space(1))) void*)g,
        (__attribute__((address_space(3))) void*)l, 16, 0, 0);
}

// ---------- MX-fp8 GEMM, BK=128 = one quant group per MFMA ----------
// 128x128 tile, 256 threads, 4 waves of 64x64 (m97 wave grid).
// LDS row = 128 B = 8 x 16B sub-chunks; rotation swizzle phys=(c+row)&7:
// each 8-lane subgroup's b128 covers all 32 banks once (conflict-free),
// and staging keeps the wave-uniform-base + lane*16 dest required by
// global_load_lds (inverse swizzle applied to the GLOBAL source).
__global__ __launch_bounds__(256) void gemm_mx_kernel(
    const unsigned char* __restrict__ A, const float* __restrict__ sx,
    const unsigned char* __restrict__ B, const float* __restrict__ swt,
    const float* __restrict__ bias, float* __restrict__ C)
{
    __shared__ unsigned char As[128 * 128];  // 16 KB
    __shared__ unsigned char Bs[128 * 128];  // 16 KB

    const int tid = threadIdx.x;
    const int m0 = blockIdx.y * 128;
    const int n0 = blockIdx.x * 128;
    const int lane = tid & 63;
    const int wid  = tid >> 6;
    const int wm = (wid & 1) * 64;
    const int wn = (wid >> 1) * 64;
    const int lr = lane & 15;
    const int lq = lane >> 4;

    floatx4 mast[4][4] = {};

    // staging: 1024 sub-chunks per buffer, 4 per thread
    const unsigned char* gA[4];
    const unsigned char* gB[4];
    int ldst[4];
    #pragma unroll
    for (int i = 0; i < 4; i++) {
        const int P = tid + i * 256;
        const int row = P >> 3, ph = P & 7;
        const int c = (ph - row) & 7;              // inverse of phys=(c+row)&7
        gA[i] = A + (size_t)(m0 + row) * K_IN + c * 16;
        gB[i] = B + (size_t)(n0 + row) * K_IN + c * 16;
        ldst[i] = P * 16;
    }

    const int col[4] = { n0 + wn + lr, n0 + wn + 16 + lr,
                         n0 + wn + 32 + lr, n0 + wn + 48 + lr };
    const floatx4 zero = {0.0f, 0.0f, 0.0f, 0.0f};

    for (int g = 0; g < 32; g++) {
        const int k0 = g * 128;
        #pragma unroll
        for (int i = 0; i < 4; i++) {
            gld16(gA[i] + k0, As + ldst[i]);
            gld16(gB[i] + k0, Bs + ldst[i]);
        }
        // per-group weight scales, coalesced ([grp][n] layout)
        float sv[4];
        #pragma unroll
        for (int ni = 0; ni < 4; ni++)
            sv[ni] = swt[(size_t)g * N_OUT + col[ni]];
        __syncthreads();

        // fragments: lane (m=lr, quad=lq) takes k-slab [lq*32, lq*32+32)
        // = logical sub-chunks {lq*2, lq*2+1} of the row
        int8v af[4], bf[4];
        #pragma unroll
        for (int mi = 0; mi < 4; mi++) {
            const int row = wm + mi * 16 + lr;
            const unsigned char* base = As + row * 128;
            const int p0 = (lq * 2 + row) & 7;
            const int p1 = (lq * 2 + 1 + row) & 7;
            int4v lo = *(const int4v*)(base + p0 * 16);
            int4v hi = *(const int4v*)(base + p1 * 16);
            af[mi] = (int8v){lo[0], lo[1], lo[2], lo[3], hi[0], hi[1], hi[2], hi[3]};
        }
        #pragma unroll
        for (int ni = 0; ni < 4; ni++) {
            const int row = wn + ni * 16 + lr;
            const unsigned char* base = Bs + row * 128;
            const int p0 = (lq * 2 + row) & 7;
            const int p1 = (lq * 2 + 1 + row) & 7;
            int4v lo = *(const int4v*)(base + p0 * 16);
            int4v hi = *(const int4v*)(base + p1 * 16);
            bf[ni] = (int8v){lo[0], lo[1], lo[2], lo[3], hi[0], hi[1], hi[2], hi[3]};
        }

        // one scaled MFMA per (mi,ni) covers the whole K=128 group exactly;
        // HW scales = 1.0 (e8m0 0x7F in every byte -> opsel-independent)
        #pragma unroll
        for (int mi = 0; mi < 4; mi++)
            #pragma unroll
            for (int ni = 0; ni < 4; ni++) {
                floatx4 t = __builtin_amdgcn_mfma_scale_f32_16x16x128_f8f6f4(
                    af[mi], bf[ni], zero, 0, 0,
                    0, 0x7F7F7F7F, 0, 0x7F7F7F7F);
                mast[mi][ni][0] += sv[ni] * t[0];
                mast[mi][ni][1] += sv[ni] * t[1];
                mast[mi][ni][2] += sv[ni] * t[2];
                mast[mi][ni][3] += sv[ni] * t[3];
            }
        __syncthreads();
    }

    // epilogue: C/D layout col=lane&15, row=(lane>>4)*4+reg [m89/m91]
    #pragma unroll
    for (int mi = 0; mi < 4; mi++) {
        const int rbase = m0 + wm + mi * 16 + lq * 4;
        #pragma unroll
        for (int ni = 0; ni < 4; ni++) {
            const float bb = bias[col[ni]];
            #pragma unroll
            for (int r = 0; r < 4; r++)
                C[(size_t)(rbase + r) * N_OUT + col[ni]] =
                    sx[rbase + r] * mast[mi][ni][r] + bb;
        }
    }
}

extern "C" void kernel_launch(void* const* d_in, const int* in_sizes, int n_in,
                              void* d_out, int out_size, void* d_ws, size_t ws_size,
                              hipStream_t stream) {
    const float* x    = (const float*)d_in[0];
    const float* w    = (const float*)d_in[1];
    const float* bias = (const float*)d_in[2];
    float* out = (float*)d_out;

    unsigned char* xq = (unsigned char*)d_ws;                       // 8 MB
    unsigned char* wq = xq + (size_t)M_TOK * K_IN;                  // 16 MB
    float* swt = (float*)(wq + (size_t)N_OUT * K_IN);               // 512 KB, [32][4096]
    float* sx  = swt + (size_t)(K_IN / 128) * N_OUT;                // 8 KB

    quant_fused_kernel<<<XBLK + WBLK, 256, 0, stream>>>(x, w, xq, sx, wq, swt);
    gemm_mx_kernel<<<dim3(N_OUT / 128, M_TOK / 128), 256, 0, stream>>>(
        xq, sx, wq, swt, bias, out);
}

// Round 5
// 174.244 us; speedup vs baseline: 1.2476x; 1.2476x over previous
//
#include <hip/hip_runtime.h>
#include <hip/hip_bf16.h>

// y = q_tok(x) @ q_grp(W)^T + bias, factored exactly:
//   q(x) = g_x * s_x[m], q(W) = g_w * s_w[n,grp] (grp=128 along K)
//   y[m,n] = s_x[m] * sum_grp s_w[n,grp] * (sum_{k in grp} g_x g_w)
// R5: quant rewritten to be memory-bound -- no divisions (thresholds
// pre-multiplied by the uniform scale), 8 elem/thread w-role, packed
// 8B stores. GEMM (MX K=128, exact group sums) unchanged from R4.

#define M_TOK 2048
#define N_OUT 4096
#define K_IN  4096
#define XBLK  2048    // x-role: one block per token row
#define WBLK  8192    // w-role: 2048 floats (16 groups) per block

typedef __attribute__((ext_vector_type(4))) int   int4v;
typedef __attribute__((ext_vector_type(8))) int   int8v;
typedef __attribute__((ext_vector_type(4))) float floatx4;

// fp4-e2m1 code as OCP e4m3 byte, chosen by |v| vs scale-premultiplied
// decision thresholds T[k] = {.25,.75,1.25,1.75,2.5,3.5,5}*scale.
// 0->0x00, .5->0x30, 1->0x38, 1.5->0x3C, 2->0x40, 3->0x44, 4->0x48, 6->0x4C
__device__ __forceinline__ unsigned int q_code(
    float v, float t0, float t1, float t2, float t3, float t4, float t5, float t6)
{
    float a = fabsf(v);
    unsigned int m =
        a < t0 ? 0x00u :
        a < t1 ? 0x30u :
        a < t2 ? 0x38u :
        a < t3 ? 0x3Cu :
        a < t4 ? 0x40u :
        a < t5 ? 0x44u :
        a < t6 ? 0x48u :
                 0x4Cu;
    return m | ((__float_as_uint(v) >> 24) & 0x80u);
}

#define MK_THR(scale) \
    const float t0 = 0.25f * (scale), t1 = 0.75f * (scale), \
                t2 = 1.25f * (scale), t3 = 1.75f * (scale), \
                t4 = 2.5f  * (scale), t5 = 3.5f  * (scale), \
                t6 = 5.0f  * (scale);

// ---------- fused quant: blocks [0,XBLK) per-token x, rest per-group w ----------
__global__ __launch_bounds__(256) void quant_fused_kernel(
    const float* __restrict__ x, const float* __restrict__ w,
    unsigned char* __restrict__ xq, float* __restrict__ sx,
    unsigned char* __restrict__ wq, float* __restrict__ swt)
{
    const int t = threadIdx.x;
    const int lane = t & 63, wid = t >> 6;

    if (blockIdx.x < XBLK) {
        // ---- per-token row of 4096: clamp [-3,3], scale = absmax/6 ----
        const int row = blockIdx.x;
        const float* xr = x + (size_t)row * K_IN;
        float vals[16];
        float amax = 0.0f;
        #pragma unroll
        for (int i = 0; i < 4; i++) {
            float4 v = *(const float4*)(xr + i * 1024 + t * 4);
            v.x = fminf(fmaxf(v.x, -3.0f), 3.0f);
            v.y = fminf(fmaxf(v.y, -3.0f), 3.0f);
            v.z = fminf(fmaxf(v.z, -3.0f), 3.0f);
            v.w = fminf(fmaxf(v.w, -3.0f), 3.0f);
            vals[i*4+0] = v.x; vals[i*4+1] = v.y; vals[i*4+2] = v.z; vals[i*4+3] = v.w;
            amax = fmaxf(amax, fmaxf(fmaxf(fabsf(v.x), fabsf(v.y)),
                                     fmaxf(fabsf(v.z), fabsf(v.w))));
        }
        #pragma unroll
        for (int off = 32; off; off >>= 1)
            amax = fmaxf(amax, __shfl_xor(amax, off));
        __shared__ float smax[4];
        if (lane == 0) smax[wid] = amax;
        __syncthreads();
        amax = fmaxf(fmaxf(smax[0], smax[1]), fmaxf(smax[2], smax[3]));

        const float scale = amax / 6.0f;
        if (t == 0) sx[row] = scale;
        MK_THR(scale);
        unsigned char* xo = xq + (size_t)row * K_IN;
        #pragma unroll
        for (int i = 0; i < 4; i++) {
            unsigned int u = q_code(vals[i*4+0], t0,t1,t2,t3,t4,t5,t6)
                           | (q_code(vals[i*4+1], t0,t1,t2,t3,t4,t5,t6) << 8)
                           | (q_code(vals[i*4+2], t0,t1,t2,t3,t4,t5,t6) << 16)
                           | (q_code(vals[i*4+3], t0,t1,t2,t3,t4,t5,t6) << 24);
            *(unsigned int*)(xo + i * 1024 + t * 4) = u;
        }
    } else {
        // ---- per-group w: block = 2048 floats = 16 groups; 16 lanes/group,
        //      8 elements per lane ----
        const int b = blockIdx.x - XBLK;
        const float* base = w + (size_t)b * 2048 + t * 8;
        float4 v0 = *(const float4*)base;
        float4 v1 = *(const float4*)(base + 4);
        float amax = fmaxf(fmaxf(fmaxf(fabsf(v0.x), fabsf(v0.y)),
                                 fmaxf(fabsf(v0.z), fabsf(v0.w))),
                           fmaxf(fmaxf(fabsf(v1.x), fabsf(v1.y)),
                                 fmaxf(fabsf(v1.z), fabsf(v1.w))));
        #pragma unroll
        for (int off = 8; off; off >>= 1)   // reduce within 16-lane cluster
            amax = fmaxf(amax, __shfl_xor(amax, off));
        const float scale = amax / 6.0f;
        const int G  = b * 16 + (t >> 4);   // flat group id = n*32 + gk
        if ((lane & 15) == 0) swt[(size_t)(G & 31) * N_OUT + (G >> 5)] = scale;
        MK_THR(scale);
        uint2 u;
        u.x = q_code(v0.x, t0,t1,t2,t3,t4,t5,t6)
            | (q_code(v0.y, t0,t1,t2,t3,t4,t5,t6) << 8)
            | (q_code(v0.z, t0,t1,t2,t3,t4,t5,t6) << 16)
            | (q_code(v0.w, t0,t1,t2,t3,t4,t5,t6) << 24);
        u.y = q_code(v1.x, t0,t1,t2,t3,t4,t5,t6)
            | (q_code(v1.y, t0,t1,t2,t3,t4,t5,t6) << 8)
            | (q_code(v1.z, t0,t1,t2,t3,t4,t5,t6) << 16)
            | (q_code(v1.w, t0,t1,t2,t3,t4,t5,t6) << 24);
        *(uint2*)(wq + (size_t)b * 2048 + t * 8) = u;
    }
}

// ---------- async 16B global->LDS ----------
__device__ __forceinline__ void gld16(const unsigned char* g, unsigned char* l) {
    __builtin_amdgcn_global_load_lds(
        (const __attribute__((address_space(1))) void*)g,
        (__attribute__((address_space(3))) void*)l, 16, 0, 0);
}

// ---------- MX-fp8 GEMM, BK=128 = one quant group per MFMA (unchanged R4) ----------
__global__ __launch_bounds__(256) void gemm_mx_kernel(
    const unsigned char* __restrict__ A, const float* __restrict__ sx,
    const unsigned char* __restrict__ B, const float* __restrict__ swt,
    const float* __restrict__ bias, float* __restrict__ C)
{
    __shared__ unsigned char As[128 * 128];  // 16 KB
    __shared__ unsigned char Bs[128 * 128];  // 16 KB

    const int tid = threadIdx.x;
    const int m0 = blockIdx.y * 128;
    const int n0 = blockIdx.x * 128;
    const int lane = tid & 63;
    const int wid  = tid >> 6;
    const int wm = (wid & 1) * 64;
    const int wn = (wid >> 1) * 64;
    const int lr = lane & 15;
    const int lq = lane >> 4;

    floatx4 mast[4][4] = {};

    // staging: 1024 sub-chunks(16B) per buffer, 4 per thread; rotation
    // swizzle phys=(c+row)&7 (inverse applied on the global source so the
    // LDS dest stays wave-uniform + lane*16)
    const unsigned char* gA[4];
    const unsigned char* gB[4];
    int ldst[4];
    #pragma unroll
    for (int i = 0; i < 4; i++) {
        const int P = tid + i * 256;
        const int row = P >> 3, ph = P & 7;
        const int c = (ph - row) & 7;
        gA[i] = A + (size_t)(m0 + row) * K_IN + c * 16;
        gB[i] = B + (size_t)(n0 + row) * K_IN + c * 16;
        ldst[i] = P * 16;
    }

    const int col[4] = { n0 + wn + lr, n0 + wn + 16 + lr,
                         n0 + wn + 32 + lr, n0 + wn + 48 + lr };
    const floatx4 zero = {0.0f, 0.0f, 0.0f, 0.0f};

    for (int g = 0; g < 32; g++) {
        const int k0 = g * 128;
        #pragma unroll
        for (int i = 0; i < 4; i++) {
            gld16(gA[i] + k0, As + ldst[i]);
            gld16(gB[i] + k0, Bs + ldst[i]);
        }
        float sv[4];
        #pragma unroll
        for (int ni = 0; ni < 4; ni++)
            sv[ni] = swt[(size_t)g * N_OUT + col[ni]];
        __syncthreads();

        // lane (m=lr, quad=lq) takes k-slab [lq*32, +32) = logical chunks {2lq, 2lq+1}
        int8v af[4], bf[4];
        #pragma unroll
        for (int mi = 0; mi < 4; mi++) {
            const int row = wm + mi * 16 + lr;
            const unsigned char* base = As + row * 128;
            const int p0 = (lq * 2 + row) & 7;
            const int p1 = (lq * 2 + 1 + row) & 7;
            int4v lo = *(const int4v*)(base + p0 * 16);
            int4v hi = *(const int4v*)(base + p1 * 16);
            af[mi] = (int8v){lo[0], lo[1], lo[2], lo[3], hi[0], hi[1], hi[2], hi[3]};
        }
        #pragma unroll
        for (int ni = 0; ni < 4; ni++) {
            const int row = wn + ni * 16 + lr;
            const unsigned char* base = Bs + row * 128;
            const int p0 = (lq * 2 + row) & 7;
            const int p1 = (lq * 2 + 1 + row) & 7;
            int4v lo = *(const int4v*)(base + p0 * 16);
            int4v hi = *(const int4v*)(base + p1 * 16);
            bf[ni] = (int8v){lo[0], lo[1], lo[2], lo[3], hi[0], hi[1], hi[2], hi[3]};
        }

        #pragma unroll
        for (int mi = 0; mi < 4; mi++)
            #pragma unroll
            for (int ni = 0; ni < 4; ni++) {
                floatx4 tacc = __builtin_amdgcn_mfma_scale_f32_16x16x128_f8f6f4(
                    af[mi], bf[ni], zero, 0, 0,
                    0, 0x7F7F7F7F, 0, 0x7F7F7F7F);
                mast[mi][ni][0] += sv[ni] * tacc[0];
                mast[mi][ni][1] += sv[ni] * tacc[1];
                mast[mi][ni][2] += sv[ni] * tacc[2];
                mast[mi][ni][3] += sv[ni] * tacc[3];
            }
        __syncthreads();
    }

    // epilogue: C/D layout col=lane&15, row=(lane>>4)*4+reg [m89/m91]
    #pragma unroll
    for (int mi = 0; mi < 4; mi++) {
        const int rbase = m0 + wm + mi * 16 + lq * 4;
        #pragma unroll
        for (int ni = 0; ni < 4; ni++) {
            const float bb = bias[col[ni]];
            #pragma unroll
            for (int r = 0; r < 4; r++)
                C[(size_t)(rbase + r) * N_OUT + col[ni]] =
                    sx[rbase + r] * mast[mi][ni][r] + bb;
        }
    }
}

extern "C" void kernel_launch(void* const* d_in, const int* in_sizes, int n_in,
                              void* d_out, int out_size, void* d_ws, size_t ws_size,
                              hipStream_t stream) {
    const float* x    = (const float*)d_in[0];
    const float* w    = (const float*)d_in[1];
    const float* bias = (const float*)d_in[2];
    float* out = (float*)d_out;

    unsigned char* xq = (unsigned char*)d_ws;                       // 8 MB
    unsigned char* wq = xq + (size_t)M_TOK * K_IN;                  // 16 MB
    float* swt = (float*)(wq + (size_t)N_OUT * K_IN);               // 512 KB, [32][4096]
    float* sx  = swt + (size_t)(K_IN / 128) * N_OUT;                // 8 KB

    quant_fused_kernel<<<XBLK + WBLK, 256, 0, stream>>>(x, w, xq, sx, wq, swt);
    gemm_mx_kernel<<<dim3(N_OUT / 128, M_TOK / 128), 256, 0, stream>>>(
        xq, sx, wq, swt, bias, out);
}